// Round 1
// baseline (9524.875 us; speedup 1.0000x reference)
//
#include <hip/hip_runtime.h>
#include <hip/hip_bf16.h>

// LSTM: B=64, T=512, IN=512, H=1024, gates order i,f,g,o (rows of 4H).
// Strategy: persistent kernel, 128 blocks x 256 threads, custom grid barrier.
// Each block owns 8 hidden units (32 gate rows). W_hh slice in per-wave
// registers (bf16 MFMA B-frags), W_ih slice in LDS, c/h state in registers.

#define Bx 64
#define Tx 512
#define INx 512
#define Hx 1024
#define NBLK 128
#define UNITS 8
#define NG 32              // 4*UNITS gate rows per block
#define LDSW (INx + 8)     // padded W_ih LDS row (2-way bank conflicts only)

typedef __attribute__((ext_vector_type(8))) short short8;
typedef __attribute__((ext_vector_type(4))) float floatx4;

__device__ __forceinline__ unsigned short f2bf(float f) {
  unsigned u = __float_as_uint(f);
  u += 0x7FFFu + ((u >> 16) & 1u);   // round-to-nearest-even
  return (unsigned short)(u >> 16);
}
__device__ __forceinline__ float sigm(float x) { return 1.0f / (1.0f + __expf(-x)); }
__device__ __forceinline__ float tanh_(float x) { return 1.0f - 2.0f / (1.0f + __expf(2.0f * x)); }

// Convert input [B][T][IN] fp32 -> xT [T][B][IN] bf16
__global__ void convert_x_kernel(const float* __restrict__ in, unsigned short* __restrict__ xT) {
  int idx = blockIdx.x * 256 + threadIdx.x;
  int lin = idx * 8;                 // output-linear index, 8 elems/thread
  int t = lin >> 15;                 // / (B*IN) = 32768
  int rem = lin & 32767;
  int b = rem >> 9;                  // / IN
  int k = rem & 511;
  const float* src = in + ((((b << 9) + t) << 9) + k);  // (b*T + t)*IN + k
  float4 lo = *(const float4*)src;
  float4 hi = *(const float4*)(src + 4);
  short8 o;
  o[0] = (short)f2bf(lo.x); o[1] = (short)f2bf(lo.y);
  o[2] = (short)f2bf(lo.z); o[3] = (short)f2bf(lo.w);
  o[4] = (short)f2bf(hi.x); o[5] = (short)f2bf(hi.y);
  o[6] = (short)f2bf(hi.z); o[7] = (short)f2bf(hi.w);
  *(short8*)(xT + lin) = o;
}

__global__ __launch_bounds__(256, 1) void lstm_persistent(
    const float* __restrict__ W_ih, const float* __restrict__ W_hh,
    const float* __restrict__ b_ih, const float* __restrict__ b_hh,
    const unsigned short* __restrict__ xT,   // [T][B][IN] bf16
    unsigned short* __restrict__ hbuf,       // [2][B][H] bf16 (zeroed)
    unsigned int* __restrict__ bar,          // 8 counters, stride 32 uints (zeroed)
    float* __restrict__ out)                 // [B][H] fp32
{
  __shared__ unsigned short wih[NG * LDSW];  // 33,280 B
  __shared__ float gsc[4][16 * 33];          // 8,448 B per-wave gate scratch

  const int tid = threadIdx.x;
  const int wv = tid >> 6;
  const int lane = tid & 63;
  const int quad = lane >> 4;
  const int col = lane & 15;
  const int bid = blockIdx.x;
  const int j0 = bid * UNITS;
  const int m0 = wv * 16;            // batch-row base for this wave

  // ---- stage W_ih slice (fp32 -> bf16) into LDS ----
  for (int idx = tid; idx < NG * INx; idx += 256) {
    int n = idx >> 9;                // / IN
    int k = idx & (INx - 1);
    int row = ((n >> 3) * Hx) + j0 + (n & 7);   // gate (n>>3), unit j0+(n&7)
    wih[n * LDSW + k] = f2bf(W_ih[row * INx + k]);
  }

  // ---- preload W_hh B-fragments into registers (identical per wave) ----
  // B-frag for 16x16x32: lane holds B[k = quad*8 + j][n = col]
  short8 wf[32][2];
#pragma unroll
  for (int kt = 0; kt < 32; ++kt) {
#pragma unroll
    for (int nt = 0; nt < 2; ++nt) {
      int n = nt * 16 + col;
      int row = ((n >> 3) * Hx) + j0 + (n & 7);
      const float* p = W_hh + row * Hx + kt * 32 + quad * 8;
      short8 w;
#pragma unroll
      for (int j = 0; j < 8; ++j) w[j] = (short)f2bf(p[j]);
      wf[kt][nt] = w;
    }
  }

  // ---- bias registers for this thread's 2 (batch,unit) pairs ----
  float bias[2][4];
#pragma unroll
  for (int p = 0; p < 2; ++p) {
    int jl = quad + 4 * p;
#pragma unroll
    for (int gt = 0; gt < 4; ++gt) {
      int row = gt * Hx + j0 + jl;
      bias[p][gt] = b_ih[row] + b_hh[row];
    }
  }

  float cst[2] = {0.0f, 0.0f};
  float hst[2] = {0.0f, 0.0f};

  __syncthreads();

  for (int t = 0; t < Tx; ++t) {
    const unsigned short* hin = hbuf + (t & 1) * (Bx * Hx);
    unsigned short* hout = hbuf + ((t + 1) & 1) * (Bx * Hx);

    floatx4 acc0 = {0.f, 0.f, 0.f, 0.f};
    floatx4 acc1 = {0.f, 0.f, 0.f, 0.f};

    // ---- recurrent part: gates += h(t) . W_hh^T ----
    // A-frag: lane holds A[m = col][k = quad*8 + j]
    const unsigned short* arow = hin + (m0 + col) * Hx + quad * 8;
#pragma unroll
    for (int kt = 0; kt < 32; ++kt) {
      short8 af = *(const short8*)(arow + kt * 32);
      acc0 = __builtin_amdgcn_mfma_f32_16x16x32_bf16(af, wf[kt][0], acc0, 0, 0, 0);
      acc1 = __builtin_amdgcn_mfma_f32_16x16x32_bf16(af, wf[kt][1], acc1, 0, 0, 0);
    }

    // ---- input part: gates += x_t . W_ih^T ----
    const unsigned short* xrow = xT + t * (Bx * INx) + (m0 + col) * INx + quad * 8;
    const unsigned short* wrow0 = wih + col * LDSW + quad * 8;
    const unsigned short* wrow1 = wih + (16 + col) * LDSW + quad * 8;
#pragma unroll
    for (int kt = 0; kt < 16; ++kt) {
      short8 af = *(const short8*)(xrow + kt * 32);
      short8 b0 = *(const short8*)(wrow0 + kt * 32);
      short8 b1 = *(const short8*)(wrow1 + kt * 32);
      acc0 = __builtin_amdgcn_mfma_f32_16x16x32_bf16(af, b0, acc0, 0, 0, 0);
      acc1 = __builtin_amdgcn_mfma_f32_16x16x32_bf16(af, b1, acc1, 0, 0, 0);
    }

    // ---- scatter gates to per-wave LDS scratch (D: row=quad*4+i, col=lane&15) ----
    float* gp = gsc[wv];
#pragma unroll
    for (int i = 0; i < 4; ++i) {
      gp[(quad * 4 + i) * 33 + col] = acc0[i];
      gp[(quad * 4 + i) * 33 + 16 + col] = acc1[i];
    }
    __syncthreads();

    // ---- activations + state update: this thread owns (m=col, j=quad & quad+4) ----
#pragma unroll
    for (int p = 0; p < 2; ++p) {
      int jl = quad + 4 * p;
      float gi = gp[col * 33 + jl] + bias[p][0];
      float gf = gp[col * 33 + 8 + jl] + bias[p][1];
      float gg = gp[col * 33 + 16 + jl] + bias[p][2];
      float go = gp[col * 33 + 24 + jl] + bias[p][3];
      float iv = sigm(gi);
      float fv = sigm(gf);
      float gv = tanh_(gg);
      float ov = sigm(go);
      float c = fv * cst[p] + iv * gv;
      cst[p] = c;
      float h = ov * tanh_(c);
      hst[p] = h;
      hout[(m0 + col) * Hx + j0 + jl] = f2bf(h);
    }
    __syncthreads();   // all waves' h stores issued & drained (s_barrier waits vmcnt)

    // ---- grid barrier: 8 leaf counters, 16 blocks each ----
    if (tid == 0) {
      __hip_atomic_fetch_add(&bar[(bid & 7) * 32], 1u, __ATOMIC_RELEASE,
                             __HIP_MEMORY_SCOPE_AGENT);
    }
    if (tid < 8) {
      unsigned target = (unsigned)(t + 1) * 16u;
      while (__hip_atomic_load(&bar[tid * 32], __ATOMIC_RELAXED,
                               __HIP_MEMORY_SCOPE_AGENT) < target) {
        __builtin_amdgcn_s_sleep(2);
      }
    }
    __syncthreads();
    __builtin_amdgcn_fence(__ATOMIC_ACQUIRE, "agent");  // invalidate stale caches
  }

  // ---- final h (kept in fp32 registers) -> out [B][1][H] ----
#pragma unroll
  for (int p = 0; p < 2; ++p) {
    int jl = quad + 4 * p;
    out[(m0 + col) * Hx + j0 + jl] = hst[p];
  }
}

extern "C" void kernel_launch(void* const* d_in, const int* in_sizes, int n_in,
                              void* d_out, int out_size, void* d_ws, size_t ws_size,
                              hipStream_t stream) {
  const float* input = (const float*)d_in[0];   // [B][T][IN]
  const float* W_ih  = (const float*)d_in[1];   // [4H][IN]
  const float* W_hh  = (const float*)d_in[2];   // [4H][H]
  const float* b_ih  = (const float*)d_in[3];   // [4H]
  const float* b_hh  = (const float*)d_in[4];   // [4H]
  float* out = (float*)d_out;

  char* ws = (char*)d_ws;
  unsigned int* bar = (unsigned int*)ws;                         // 8 x 128B
  unsigned short* hbuf = (unsigned short*)(ws + 1024);           // 256 KB
  unsigned short* xT = (unsigned short*)(ws + (512u << 10));     // 32 MB

  // zero barrier counters + h double-buffer (h0 = initial state = 0)
  hipMemsetAsync(ws, 0, 1024 + 2 * Bx * Hx * sizeof(unsigned short), stream);

  convert_x_kernel<<<(Bx * Tx * INx) / (256 * 8), 256, 0, stream>>>(input, xT);

  lstm_persistent<<<NBLK, 256, 0, stream>>>(W_ih, W_hh, b_ih, b_hh, xT, hbuf, bar, out);
}

// Round 2
// 7724.720 us; speedup vs baseline: 1.2330x; 1.2330x over previous
//
#include <hip/hip_runtime.h>
#include <hip/hip_bf16.h>

// LSTM: B=64, T=512, IN=512, H=1024, gates i,f,g,o.
// Persistent kernel, 128 blocks x 256 threads, custom grid barrier.
// R2: h staged to LDS via global_load_lds (XOR-swizzled, conflict-free,
// zero padding), x A-frags prefetched to registers, W_hh in registers,
// W_ih bf16-swizzled in LDS. Gate scratch overlapped onto h LDS region.

#define Bx 64
#define Tx 512
#define INx 512
#define Hx 1024
#define NBLK 128
#define UNITS 8

typedef __attribute__((ext_vector_type(8))) short short8;
typedef __attribute__((ext_vector_type(4))) float floatx4;

#define ASYNC_CP(gp, lp)                                                      \
  __builtin_amdgcn_global_load_lds(                                           \
      (const __attribute__((address_space(1))) void*)(gp),                    \
      (__attribute__((address_space(3))) void*)(lp), 16, 0, 0)

__device__ __forceinline__ unsigned short f2bf(float f) {
  unsigned u = __float_as_uint(f);
  u += 0x7FFFu + ((u >> 16) & 1u);   // round-to-nearest-even
  return (unsigned short)(u >> 16);
}
__device__ __forceinline__ float sigm(float x) { return 1.0f / (1.0f + __expf(-x)); }
__device__ __forceinline__ float tanh_(float x) { return 1.0f - 2.0f / (1.0f + __expf(2.0f * x)); }

// Convert input [B][T][IN] fp32 -> xT [T][B][IN] bf16
__global__ void convert_x_kernel(const float* __restrict__ in, unsigned short* __restrict__ xT) {
  int idx = blockIdx.x * 256 + threadIdx.x;
  int lin = idx * 8;
  int t = lin >> 15;
  int rem = lin & 32767;
  int b = rem >> 9;
  int k = rem & 511;
  const float* src = in + ((((b << 9) + t) << 9) + k);
  float4 lo = *(const float4*)src;
  float4 hi = *(const float4*)(src + 4);
  short8 o;
  o[0] = (short)f2bf(lo.x); o[1] = (short)f2bf(lo.y);
  o[2] = (short)f2bf(lo.z); o[3] = (short)f2bf(lo.w);
  o[4] = (short)f2bf(hi.x); o[5] = (short)f2bf(hi.y);
  o[6] = (short)f2bf(hi.z); o[7] = (short)f2bf(hi.w);
  *(short8*)(xT + lin) = o;
}

__global__ __launch_bounds__(256, 1) void lstm_persistent(
    const float* __restrict__ W_ih, const float* __restrict__ W_hh,
    const float* __restrict__ b_ih, const float* __restrict__ b_hh,
    const unsigned short* __restrict__ xT,   // [T][B][IN] bf16
    unsigned short* __restrict__ hbuf,       // [2][B][H] bf16 (zeroed)
    unsigned int* __restrict__ bar,          // 8 counters, stride 32 uints (zeroed)
    float* __restrict__ out)                 // [B][H] fp32
{
  // h: 64 rows x 1024 shorts, 16B-chunk c of row m stored at c^(m&7)  (128 KiB)
  // wih: 32 rows x 512 shorts, chunk c of row n stored at c^(n&7)     (32 KiB)
  __shared__ short hsh[Bx * Hx];
  __shared__ short wsh[32 * INx];

  const int tid = threadIdx.x;
  const int wv = tid >> 6;
  const int lane = tid & 63;
  const int quad = lane >> 4;
  const int col = lane & 15;
  const int swz = col & 7;
  const int bid = blockIdx.x;
  const int j0 = bid * UNITS;
  const int m0 = wv * 16;            // batch-row base for this wave

  // ---- stage W_ih slice (fp32 -> bf16, swizzled) into LDS ----
  for (int idx = tid; idx < 32 * INx; idx += 256) {
    int n = idx >> 9;
    int k = idx & (INx - 1);
    int row = ((n >> 3) * Hx) + j0 + (n & 7);
    int c = k >> 3;
    wsh[n * INx + (((c ^ (n & 7)) << 3) | (k & 7))] = f2bf(W_ih[row * INx + k]);
  }

  // ---- preload W_hh B-fragments into registers ----
  short8 wf[32][2];
#pragma unroll
  for (int kt = 0; kt < 32; ++kt) {
#pragma unroll
    for (int nt = 0; nt < 2; ++nt) {
      int n = nt * 16 + col;
      int row = ((n >> 3) * Hx) + j0 + (n & 7);
      const float* p = W_hh + row * Hx + kt * 32 + quad * 8;
      short8 w;
#pragma unroll
      for (int j = 0; j < 8; ++j) w[j] = (short)f2bf(p[j]);
      wf[kt][nt] = w;
    }
  }

  // ---- bias registers ----
  float bias[2][4];
#pragma unroll
  for (int p = 0; p < 2; ++p) {
    int jl = quad + 4 * p;
#pragma unroll
    for (int gt = 0; gt < 4; ++gt) {
      int row = gt * Hx + j0 + jl;
      bias[p][gt] = b_ih[row] + b_hh[row];
    }
  }

  float cst[2] = {0.0f, 0.0f};
  float hst[2] = {0.0f, 0.0f};

  __syncthreads();

  for (int t = 0; t < Tx; ++t) {
    const unsigned short* hin = hbuf + (t & 1) * (Bx * Hx);
    unsigned short* hout = hbuf + ((t + 1) & 1) * (Bx * Hx);

    // ---- stage this wave's 16 h rows into LDS (swizzled, async DMA) ----
#pragma unroll
    for (int r = 0; r < 16; ++r) {
      const unsigned short* g = hin + (m0 + r) * Hx + ((lane ^ (r & 7)) << 3);
      short* l = hsh + (m0 + r) * Hx;
      ASYNC_CP(g, l);
      ASYNC_CP(g + 512, l + 512);
    }

    // ---- prefetch x A-frags into registers ----
    short8 xa[16];
    const unsigned short* xrow =
        xT + (size_t)t * (Bx * INx) + (m0 + col) * INx + quad * 8;
#pragma unroll
    for (int kt = 0; kt < 16; ++kt) xa[kt] = *(const short8*)(xrow + kt * 32);

    floatx4 a0a = {0.f, 0.f, 0.f, 0.f}, a0b = {0.f, 0.f, 0.f, 0.f};
    floatx4 a1a = {0.f, 0.f, 0.f, 0.f}, a1b = {0.f, 0.f, 0.f, 0.f};

    // ---- recurrent part: gates += h(t) . W_hh^T  (A from LDS, B in regs) ----
    const short* ab = hsh + (m0 + col) * Hx;
#pragma unroll
    for (int kt = 0; kt < 32; ++kt) {
      short8 af = *(const short8*)(ab + ((((kt << 2) | quad) ^ swz) << 3));
      if (kt & 1) {
        a0b = __builtin_amdgcn_mfma_f32_16x16x32_bf16(af, wf[kt][0], a0b, 0, 0, 0);
        a1b = __builtin_amdgcn_mfma_f32_16x16x32_bf16(af, wf[kt][1], a1b, 0, 0, 0);
      } else {
        a0a = __builtin_amdgcn_mfma_f32_16x16x32_bf16(af, wf[kt][0], a0a, 0, 0, 0);
        a1a = __builtin_amdgcn_mfma_f32_16x16x32_bf16(af, wf[kt][1], a1a, 0, 0, 0);
      }
    }

    // ---- input part: gates += x_t . W_ih^T  (A in regs, B from LDS) ----
    const short* b0base = wsh + col * INx;
    const short* b1base = wsh + (col + 16) * INx;
#pragma unroll
    for (int kt = 0; kt < 16; ++kt) {
      int off = (((kt << 2) | quad) ^ swz) << 3;
      short8 b0 = *(const short8*)(b0base + off);
      short8 b1 = *(const short8*)(b1base + off);
      if (kt & 1) {
        a0b = __builtin_amdgcn_mfma_f32_16x16x32_bf16(xa[kt], b0, a0b, 0, 0, 0);
        a1b = __builtin_amdgcn_mfma_f32_16x16x32_bf16(xa[kt], b1, a1b, 0, 0, 0);
      } else {
        a0a = __builtin_amdgcn_mfma_f32_16x16x32_bf16(xa[kt], b0, a0a, 0, 0, 0);
        a1a = __builtin_amdgcn_mfma_f32_16x16x32_bf16(xa[kt], b1, a1a, 0, 0, 0);
      }
    }
    floatx4 acc0 = a0a + a0b;
    floatx4 acc1 = a1a + a1b;

    // ---- transpose gates via per-wave scratch overlapped onto own h region ----
    float* gp = (float*)(hsh + wv * 16 * Hx);
#pragma unroll
    for (int i = 0; i < 4; ++i) {
      gp[(quad * 4 + i) * 33 + col] = acc0[i];
      gp[(quad * 4 + i) * 33 + 16 + col] = acc1[i];
    }

    // ---- activations + state update: thread owns (m=col, j=quad & quad+4) ----
#pragma unroll
    for (int p = 0; p < 2; ++p) {
      int jl = quad + 4 * p;
      float gi = gp[col * 33 + jl] + bias[p][0];
      float gf = gp[col * 33 + 8 + jl] + bias[p][1];
      float gg = gp[col * 33 + 16 + jl] + bias[p][2];
      float go = gp[col * 33 + 24 + jl] + bias[p][3];
      float iv = sigm(gi);
      float fv = sigm(gf);
      float gv = tanh_(gg);
      float ov = sigm(go);
      float c = fv * cst[p] + iv * gv;
      cst[p] = c;
      float h = ov * tanh_(c);
      hst[p] = h;
      hout[(m0 + col) * Hx + j0 + jl] = f2bf(h);
    }
    __syncthreads();   // drain all waves' h stores before arrival

    // ---- grid barrier: 8 leaf counters, 16 blocks each ----
    if (tid == 0) {
      __hip_atomic_fetch_add(&bar[(bid & 7) * 32], 1u, __ATOMIC_RELEASE,
                             __HIP_MEMORY_SCOPE_AGENT);
    }
    if (tid < 8) {
      unsigned target = (unsigned)(t + 1) * 16u;
      while (__hip_atomic_load(&bar[tid * 32], __ATOMIC_RELAXED,
                               __HIP_MEMORY_SCOPE_AGENT) < target) {
        __builtin_amdgcn_s_sleep(1);
      }
    }
    __syncthreads();
    __builtin_amdgcn_fence(__ATOMIC_ACQUIRE, "agent");
  }

  // ---- final h -> out [B][1][H] ----
#pragma unroll
  for (int p = 0; p < 2; ++p) {
    int jl = quad + 4 * p;
    out[(m0 + col) * Hx + j0 + jl] = hst[p];
  }
}

extern "C" void kernel_launch(void* const* d_in, const int* in_sizes, int n_in,
                              void* d_out, int out_size, void* d_ws, size_t ws_size,
                              hipStream_t stream) {
  const float* input = (const float*)d_in[0];   // [B][T][IN]
  const float* W_ih  = (const float*)d_in[1];   // [4H][IN]
  const float* W_hh  = (const float*)d_in[2];   // [4H][H]
  const float* b_ih  = (const float*)d_in[3];   // [4H]
  const float* b_hh  = (const float*)d_in[4];   // [4H]
  float* out = (float*)d_out;

  char* ws = (char*)d_ws;
  unsigned int* bar = (unsigned int*)ws;                         // 8 x 128B
  unsigned short* hbuf = (unsigned short*)(ws + 1024);           // 256 KB
  unsigned short* xT = (unsigned short*)(ws + (512u << 10));     // 32 MB

  hipMemsetAsync(ws, 0, 1024 + 2 * Bx * Hx * sizeof(unsigned short), stream);

  convert_x_kernel<<<(Bx * Tx * INx) / (256 * 8), 256, 0, stream>>>(input, xT);

  lstm_persistent<<<NBLK, 256, 0, stream>>>(W_ih, W_hh, b_ih, b_hh, xT, hbuf, bar, out);
}

// Round 3
// 4097.428 us; speedup vs baseline: 2.3246x; 1.8853x over previous
//
#include <hip/hip_runtime.h>
#include <hip/hip_bf16.h>

// LSTM: B=64, T=512, IN=512, H=1024, gates i,f,g,o.
// Persistent kernel, 128 blocks x 256 threads, custom grid barrier.
// R3: NO per-step fences (no buffer_wbl2/buffer_inv). All cross-block
// traffic is device-scope (sc1): h stores = packed 4B relaxed-agent atomic
// stores; h loads = global_load_lds with aux=16 (SC1); barrier = relaxed
// atomics. L2 stays warm for x/W reads. W_hh in regs, W_ih bf16 in LDS,
// XOR-swizzled conflict-free layouts.

#define Bx 64
#define Tx 512
#define INx 512
#define Hx 1024
#define NBLK 128
#define UNITS 8
#define CPOL_SC1 16   // gfx9 CPol: SC1 bit -> device-scope (cross-XCD coherent)

typedef __attribute__((ext_vector_type(8))) short short8;
typedef __attribute__((ext_vector_type(4))) float floatx4;

#define ASYNC_CP_SC1(gp, lp)                                                  \
  __builtin_amdgcn_global_load_lds(                                           \
      (const __attribute__((address_space(1))) void*)(gp),                    \
      (__attribute__((address_space(3))) void*)(lp), 16, 0, CPOL_SC1)

__device__ __forceinline__ unsigned short f2bf(float f) {
  unsigned u = __float_as_uint(f);
  u += 0x7FFFu + ((u >> 16) & 1u);   // round-to-nearest-even
  return (unsigned short)(u >> 16);
}
__device__ __forceinline__ float sigm(float x) { return 1.0f / (1.0f + __expf(-x)); }
__device__ __forceinline__ float tanh_(float x) { return 1.0f - 2.0f / (1.0f + __expf(2.0f * x)); }

// Convert input [B][T][IN] fp32 -> xT [T][B][IN] bf16
__global__ void convert_x_kernel(const float* __restrict__ in, unsigned short* __restrict__ xT) {
  int idx = blockIdx.x * 256 + threadIdx.x;
  int lin = idx * 8;
  int t = lin >> 15;
  int rem = lin & 32767;
  int b = rem >> 9;
  int k = rem & 511;
  const float* src = in + ((((b << 9) + t) << 9) + k);
  float4 lo = *(const float4*)src;
  float4 hi = *(const float4*)(src + 4);
  short8 o;
  o[0] = (short)f2bf(lo.x); o[1] = (short)f2bf(lo.y);
  o[2] = (short)f2bf(lo.z); o[3] = (short)f2bf(lo.w);
  o[4] = (short)f2bf(hi.x); o[5] = (short)f2bf(hi.y);
  o[6] = (short)f2bf(hi.z); o[7] = (short)f2bf(hi.w);
  *(short8*)(xT + lin) = o;
}

__global__ __launch_bounds__(256, 1) void lstm_persistent(
    const float* __restrict__ W_ih, const float* __restrict__ W_hh,
    const float* __restrict__ b_ih, const float* __restrict__ b_hh,
    const unsigned short* __restrict__ xT,   // [T][B][IN] bf16
    unsigned short* __restrict__ hbuf,       // [2][B][H] bf16 (zeroed)
    unsigned int* __restrict__ bar,          // 8 counters, stride 32 uints (zeroed)
    float* __restrict__ out)                 // [B][H] fp32
{
  // h: 64 rows x 1024 shorts, 16B-chunk c of row m stored at c^(m&7)  (128 KiB)
  // wih: 32 rows x 512 shorts, chunk c of row n stored at c^(n&7)     (32 KiB)
  __shared__ short hsh[Bx * Hx];
  __shared__ short wsh[32 * INx];

  const int tid = threadIdx.x;
  const int wv = tid >> 6;
  const int lane = tid & 63;
  const int quad = lane >> 4;
  const int col = lane & 15;
  const int swz = col & 7;
  const int bid = blockIdx.x;
  const int j0 = bid * UNITS;
  const int m0 = wv * 16;            // batch-row base for this wave

  // ---- stage W_ih slice (fp32 -> bf16, swizzled) into LDS ----
  for (int idx = tid; idx < 32 * INx; idx += 256) {
    int n = idx >> 9;
    int k = idx & (INx - 1);
    int row = ((n >> 3) * Hx) + j0 + (n & 7);
    int c = k >> 3;
    wsh[n * INx + (((c ^ (n & 7)) << 3) | (k & 7))] = f2bf(W_ih[row * INx + k]);
  }

  // ---- preload W_hh B-fragments into registers ----
  short8 wf[32][2];
#pragma unroll
  for (int kt = 0; kt < 32; ++kt) {
#pragma unroll
    for (int nt = 0; nt < 2; ++nt) {
      int n = nt * 16 + col;
      int row = ((n >> 3) * Hx) + j0 + (n & 7);
      const float* p = W_hh + row * Hx + kt * 32 + quad * 8;
      short8 w;
#pragma unroll
      for (int j = 0; j < 8; ++j) w[j] = (short)f2bf(p[j]);
      wf[kt][nt] = w;
    }
  }

  // ---- bias registers: this thread owns (m=m0+col, units j0+2*quad+{0,1}) ----
  float bias[2][4];
#pragma unroll
  for (int p = 0; p < 2; ++p) {
    int jl = 2 * quad + p;
#pragma unroll
    for (int gt = 0; gt < 4; ++gt) {
      int row = gt * Hx + j0 + jl;
      bias[p][gt] = b_ih[row] + b_hh[row];
    }
  }

  float cst[2] = {0.0f, 0.0f};
  float hst[2] = {0.0f, 0.0f};

  __syncthreads();

  for (int t = 0; t < Tx; ++t) {
    const unsigned short* hin = hbuf + (t & 1) * (Bx * Hx);
    unsigned short* hout = hbuf + ((t + 1) & 1) * (Bx * Hx);

    // ---- stage this wave's 16 h rows into LDS (swizzled, device-scope DMA) ----
#pragma unroll
    for (int r = 0; r < 16; ++r) {
      const unsigned short* g = hin + (m0 + r) * Hx + ((lane ^ (r & 7)) << 3);
      short* l = hsh + (m0 + r) * Hx;
      ASYNC_CP_SC1(g, l);
      ASYNC_CP_SC1(g + 512, l + 512);
    }

    // ---- prefetch x A-frags into registers (normal cached loads, L2-warm) ----
    short8 xa[16];
    const unsigned short* xrow =
        xT + (size_t)t * (Bx * INx) + (m0 + col) * INx + quad * 8;
#pragma unroll
    for (int kt = 0; kt < 16; ++kt) xa[kt] = *(const short8*)(xrow + kt * 32);

    floatx4 a0a = {0.f, 0.f, 0.f, 0.f}, a0b = {0.f, 0.f, 0.f, 0.f};
    floatx4 a1a = {0.f, 0.f, 0.f, 0.f}, a1b = {0.f, 0.f, 0.f, 0.f};

    // ---- recurrent part: gates += h(t) . W_hh^T  (A from LDS, B in regs) ----
    const short* ab = hsh + (m0 + col) * Hx;
#pragma unroll
    for (int kt = 0; kt < 32; ++kt) {
      short8 af = *(const short8*)(ab + ((((kt << 2) | quad) ^ swz) << 3));
      if (kt & 1) {
        a0b = __builtin_amdgcn_mfma_f32_16x16x32_bf16(af, wf[kt][0], a0b, 0, 0, 0);
        a1b = __builtin_amdgcn_mfma_f32_16x16x32_bf16(af, wf[kt][1], a1b, 0, 0, 0);
      } else {
        a0a = __builtin_amdgcn_mfma_f32_16x16x32_bf16(af, wf[kt][0], a0a, 0, 0, 0);
        a1a = __builtin_amdgcn_mfma_f32_16x16x32_bf16(af, wf[kt][1], a1a, 0, 0, 0);
      }
    }

    // ---- input part: gates += x_t . W_ih^T  (A in regs, B from LDS) ----
    const short* b0base = wsh + col * INx;
    const short* b1base = wsh + (col + 16) * INx;
#pragma unroll
    for (int kt = 0; kt < 16; ++kt) {
      int off = (((kt << 2) | quad) ^ swz) << 3;
      short8 b0 = *(const short8*)(b0base + off);
      short8 b1 = *(const short8*)(b1base + off);
      if (kt & 1) {
        a0b = __builtin_amdgcn_mfma_f32_16x16x32_bf16(xa[kt], b0, a0b, 0, 0, 0);
        a1b = __builtin_amdgcn_mfma_f32_16x16x32_bf16(xa[kt], b1, a1b, 0, 0, 0);
      } else {
        a0a = __builtin_amdgcn_mfma_f32_16x16x32_bf16(xa[kt], b0, a0a, 0, 0, 0);
        a1a = __builtin_amdgcn_mfma_f32_16x16x32_bf16(xa[kt], b1, a1a, 0, 0, 0);
      }
    }
    floatx4 acc0 = a0a + a0b;
    floatx4 acc1 = a1a + a1b;

    // ---- transpose gates via per-wave scratch overlapped onto own h region ----
    float* gp = (float*)(hsh + wv * 16 * Hx);
#pragma unroll
    for (int i = 0; i < 4; ++i) {
      gp[(quad * 4 + i) * 33 + col] = acc0[i];
      gp[(quad * 4 + i) * 33 + 16 + col] = acc1[i];
    }

    // ---- activations: thread owns (m=m0+col, units jl=2*quad+{0,1}) ----
    unsigned int hpack = 0;
#pragma unroll
    for (int p = 0; p < 2; ++p) {
      int jl = 2 * quad + p;
      float gi = gp[col * 33 + jl] + bias[p][0];
      float gf = gp[col * 33 + 8 + jl] + bias[p][1];
      float gg = gp[col * 33 + 16 + jl] + bias[p][2];
      float go = gp[col * 33 + 24 + jl] + bias[p][3];
      float iv = sigm(gi);
      float fv = sigm(gf);
      float gv = tanh_(gg);
      float ov = sigm(go);
      float c = fv * cst[p] + iv * gv;
      cst[p] = c;
      float h = ov * tanh_(c);
      hst[p] = h;
      hpack |= ((unsigned int)f2bf(h)) << (16 * p);
    }
    // device-scope (sc1) packed store: visible at LLC once vmcnt-drained
    __hip_atomic_store(
        (unsigned int*)(hout + (m0 + col) * Hx + j0 + 2 * quad), hpack,
        __ATOMIC_RELAXED, __HIP_MEMORY_SCOPE_AGENT);

    __syncthreads();   // drains vmcnt(0) before s_barrier -> h stores complete

    // ---- grid barrier: 8 leaf counters, 16 blocks each, all relaxed ----
    if (tid == 0) {
      __hip_atomic_fetch_add(&bar[(bid & 7) * 32], 1u, __ATOMIC_RELAXED,
                             __HIP_MEMORY_SCOPE_AGENT);
    }
    if (tid < 8) {
      unsigned target = (unsigned)(t + 1) * 16u;
      while (__hip_atomic_load(&bar[tid * 32], __ATOMIC_RELAXED,
                               __HIP_MEMORY_SCOPE_AGENT) < target) {
        __builtin_amdgcn_s_sleep(1);
      }
    }
    __syncthreads();   // also prevents hoisting next step's DMA above the spin
  }

  // ---- final h -> out [B][1][H] ----
#pragma unroll
  for (int p = 0; p < 2; ++p) {
    int jl = 2 * quad + p;
    out[(m0 + col) * Hx + j0 + jl] = hst[p];
  }
}

extern "C" void kernel_launch(void* const* d_in, const int* in_sizes, int n_in,
                              void* d_out, int out_size, void* d_ws, size_t ws_size,
                              hipStream_t stream) {
  const float* input = (const float*)d_in[0];   // [B][T][IN]
  const float* W_ih  = (const float*)d_in[1];   // [4H][IN]
  const float* W_hh  = (const float*)d_in[2];   // [4H][H]
  const float* b_ih  = (const float*)d_in[3];   // [4H]
  const float* b_hh  = (const float*)d_in[4];   // [4H]
  float* out = (float*)d_out;

  char* ws = (char*)d_ws;
  unsigned int* bar = (unsigned int*)ws;                         // 8 x 128B
  unsigned short* hbuf = (unsigned short*)(ws + 1024);           // 256 KB
  unsigned short* xT = (unsigned short*)(ws + (512u << 10));     // 32 MB

  hipMemsetAsync(ws, 0, 1024 + 2 * Bx * Hx * sizeof(unsigned short), stream);

  convert_x_kernel<<<(Bx * Tx * INx) / (256 * 8), 256, 0, stream>>>(input, xT);

  lstm_persistent<<<NBLK, 256, 0, stream>>>(W_ih, W_hh, b_ih, b_hh, xT, hbuf, bar, out);
}

// Round 4
// 3527.328 us; speedup vs baseline: 2.7003x; 1.1616x over previous
//
#include <hip/hip_runtime.h>
#include <hip/hip_bf16.h>

// LSTM: B=64, T=512, IN=512, H=1024, gates i,f,g,o.
// Persistent kernel, 128 blocks x 256 threads, custom grid barrier.
// R4: h broadcast made L2-cacheable: 65 rotating h buffers; writers store
// sc1 (LLC write-through), readers use NORMAL cached global_load_lds so 16
// blocks/XCD share one L2 fill (16x less fabric traffic than R3's sc1 DMA).
// Acquire fence every 32 steps kills any stale L2 line before address reuse
// (reuse distance = 65 steps). x A-frags for t+1 prefetched before the
// barrier spin. W_hh in regs, W_ih bf16 in LDS, XOR-swizzled layouts.

#define Bx 64
#define Tx 512
#define INx 512
#define Hx 1024
#define NBLK 128
#define UNITS 8
#define NBUF 65            // rotating h buffers

typedef __attribute__((ext_vector_type(8))) short short8;
typedef __attribute__((ext_vector_type(4))) float floatx4;

// normal cached direct-to-LDS copy (L2-allocating)
#define ASYNC_CP(gp, lp)                                                      \
  __builtin_amdgcn_global_load_lds(                                           \
      (const __attribute__((address_space(1))) void*)(gp),                    \
      (__attribute__((address_space(3))) void*)(lp), 16, 0, 0)

__device__ __forceinline__ unsigned short f2bf(float f) {
  unsigned u = __float_as_uint(f);
  u += 0x7FFFu + ((u >> 16) & 1u);   // round-to-nearest-even
  return (unsigned short)(u >> 16);
}
__device__ __forceinline__ float sigm(float x) { return 1.0f / (1.0f + __expf(-x)); }
__device__ __forceinline__ float tanh_(float x) { return 1.0f - 2.0f / (1.0f + __expf(2.0f * x)); }

// Convert input [B][T][IN] fp32 -> xT [T][B][IN] bf16
__global__ void convert_x_kernel(const float* __restrict__ in, unsigned short* __restrict__ xT) {
  int idx = blockIdx.x * 256 + threadIdx.x;
  int lin = idx * 8;
  int t = lin >> 15;
  int rem = lin & 32767;
  int b = rem >> 9;
  int k = rem & 511;
  const float* src = in + ((((b << 9) + t) << 9) + k);
  float4 lo = *(const float4*)src;
  float4 hi = *(const float4*)(src + 4);
  short8 o;
  o[0] = (short)f2bf(lo.x); o[1] = (short)f2bf(lo.y);
  o[2] = (short)f2bf(lo.z); o[3] = (short)f2bf(lo.w);
  o[4] = (short)f2bf(hi.x); o[5] = (short)f2bf(hi.y);
  o[6] = (short)f2bf(hi.z); o[7] = (short)f2bf(hi.w);
  *(short8*)(xT + lin) = o;
}

__global__ __launch_bounds__(256, 1) void lstm_persistent(
    const float* __restrict__ W_ih, const float* __restrict__ W_hh,
    const float* __restrict__ b_ih, const float* __restrict__ b_hh,
    const unsigned short* __restrict__ xT,   // [T][B][IN] bf16
    unsigned short* __restrict__ hbuf,       // [NBUF][B][H] bf16 (buf 0 zeroed)
    unsigned int* __restrict__ bar,          // 8 counters, stride 32 uints (zeroed)
    float* __restrict__ out)                 // [B][H] fp32
{
  // h: 64 rows x 1024 shorts, 16B-chunk c of row m at c^(m&7)   (128 KiB)
  // wih: 32 rows x 512 shorts, chunk c of row n at c^(n&7)      (32 KiB)
  __shared__ short hsh[Bx * Hx];
  __shared__ short wsh[32 * INx];

  const int tid = threadIdx.x;
  const int wv = tid >> 6;
  const int lane = tid & 63;
  const int quad = lane >> 4;
  const int col = lane & 15;
  const int swz = col & 7;
  const int bid = blockIdx.x;
  const int j0 = bid * UNITS;
  const int m0 = wv * 16;            // batch-row base for this wave

  // ---- stage W_ih slice (fp32 -> bf16, swizzled) into LDS ----
  for (int idx = tid; idx < 32 * INx; idx += 256) {
    int n = idx >> 9;
    int k = idx & (INx - 1);
    int row = ((n >> 3) * Hx) + j0 + (n & 7);
    int c = k >> 3;
    wsh[n * INx + (((c ^ (n & 7)) << 3) | (k & 7))] = f2bf(W_ih[row * INx + k]);
  }

  // ---- preload W_hh B-fragments into registers ----
  short8 wf[32][2];
#pragma unroll
  for (int kt = 0; kt < 32; ++kt) {
#pragma unroll
    for (int nt = 0; nt < 2; ++nt) {
      int n = nt * 16 + col;
      int row = ((n >> 3) * Hx) + j0 + (n & 7);
      const float* p = W_hh + row * Hx + kt * 32 + quad * 8;
      short8 w;
#pragma unroll
      for (int j = 0; j < 8; ++j) w[j] = (short)f2bf(p[j]);
      wf[kt][nt] = w;
    }
  }

  // ---- bias registers: thread owns (m=m0+col, units j0+2*quad+{0,1}) ----
  float bias[2][4];
#pragma unroll
  for (int p = 0; p < 2; ++p) {
    int jl = 2 * quad + p;
#pragma unroll
    for (int gt = 0; gt < 4; ++gt) {
      int row = gt * Hx + j0 + jl;
      bias[p][gt] = b_ih[row] + b_hh[row];
    }
  }

  float cst[2] = {0.0f, 0.0f};
  float hst[2] = {0.0f, 0.0f};

  // ---- prefetch x A-frags for t=0 ----
  short8 xa[16];
  {
    const unsigned short* xrow = xT + (m0 + col) * INx + quad * 8;
#pragma unroll
    for (int kt = 0; kt < 16; ++kt) xa[kt] = *(const short8*)(xrow + kt * 32);
  }

  __syncthreads();

  int ridx = 0;                      // t % NBUF
  for (int t = 0; t < Tx; ++t) {
    int widx = ridx + 1; if (widx == NBUF) widx = 0;
    const unsigned short* hin = hbuf + (size_t)ridx * (Bx * Hx);
    unsigned short* hout = hbuf + (size_t)widx * (Bx * Hx);
    ridx = widx;

    // ---- stage this wave's 16 h rows into LDS (cached, L2-shared) ----
#pragma unroll
    for (int r = 0; r < 16; ++r) {
      const unsigned short* g = hin + (m0 + r) * Hx + ((lane ^ (r & 7)) << 3);
      short* l = hsh + (m0 + r) * Hx;
      ASYNC_CP(g, l);
      ASYNC_CP(g + 512, l + 512);
    }

    floatx4 a0a = {0.f, 0.f, 0.f, 0.f}, a0b = {0.f, 0.f, 0.f, 0.f};
    floatx4 a1a = {0.f, 0.f, 0.f, 0.f}, a1b = {0.f, 0.f, 0.f, 0.f};

    // ---- input part first (independent of h DMA): gates += x_t . W_ih^T ----
    const short* b0base = wsh + col * INx;
    const short* b1base = wsh + (col + 16) * INx;
#pragma unroll
    for (int kt = 0; kt < 16; ++kt) {
      int off = (((kt << 2) | quad) ^ swz) << 3;
      short8 b0 = *(const short8*)(b0base + off);
      short8 b1 = *(const short8*)(b1base + off);
      if (kt & 1) {
        a0b = __builtin_amdgcn_mfma_f32_16x16x32_bf16(xa[kt], b0, a0b, 0, 0, 0);
        a1b = __builtin_amdgcn_mfma_f32_16x16x32_bf16(xa[kt], b1, a1b, 0, 0, 0);
      } else {
        a0a = __builtin_amdgcn_mfma_f32_16x16x32_bf16(xa[kt], b0, a0a, 0, 0, 0);
        a1a = __builtin_amdgcn_mfma_f32_16x16x32_bf16(xa[kt], b1, a1a, 0, 0, 0);
      }
    }

    // ---- recurrent part: gates += h(t) . W_hh^T  (A from LDS, B in regs) ----
    const short* ab = hsh + (m0 + col) * Hx;
#pragma unroll
    for (int kt = 0; kt < 32; ++kt) {
      short8 af = *(const short8*)(ab + ((((kt << 2) | quad) ^ swz) << 3));
      if (kt & 1) {
        a0b = __builtin_amdgcn_mfma_f32_16x16x32_bf16(af, wf[kt][0], a0b, 0, 0, 0);
        a1b = __builtin_amdgcn_mfma_f32_16x16x32_bf16(af, wf[kt][1], a1b, 0, 0, 0);
      } else {
        a0a = __builtin_amdgcn_mfma_f32_16x16x32_bf16(af, wf[kt][0], a0a, 0, 0, 0);
        a1a = __builtin_amdgcn_mfma_f32_16x16x32_bf16(af, wf[kt][1], a1a, 0, 0, 0);
      }
    }
    floatx4 acc0 = a0a + a0b;
    floatx4 acc1 = a1a + a1b;

    // ---- transpose gates via per-wave scratch overlapped onto own h region ----
    float* gp = (float*)(hsh + wv * 16 * Hx);
#pragma unroll
    for (int i = 0; i < 4; ++i) {
      gp[(quad * 4 + i) * 33 + col] = acc0[i];
      gp[(quad * 4 + i) * 33 + 16 + col] = acc1[i];
    }

    // ---- activations: thread owns (m=m0+col, units jl=2*quad+{0,1}) ----
    unsigned int hpack = 0;
#pragma unroll
    for (int p = 0; p < 2; ++p) {
      int jl = 2 * quad + p;
      float gi = gp[col * 33 + jl] + bias[p][0];
      float gf = gp[col * 33 + 8 + jl] + bias[p][1];
      float gg = gp[col * 33 + 16 + jl] + bias[p][2];
      float go = gp[col * 33 + 24 + jl] + bias[p][3];
      float iv = sigm(gi);
      float fv = sigm(gf);
      float gv = tanh_(gg);
      float ov = sigm(go);
      float c = fv * cst[p] + iv * gv;
      cst[p] = c;
      float h = ov * tanh_(c);
      hst[p] = h;
      hpack |= ((unsigned int)f2bf(h)) << (16 * p);
    }
    // device-scope (sc1) packed store: visible at LLC once vmcnt-drained
    __hip_atomic_store(
        (unsigned int*)(hout + (m0 + col) * Hx + j0 + 2 * quad), hpack,
        __ATOMIC_RELAXED, __HIP_MEMORY_SCOPE_AGENT);

    // ---- prefetch x A-frags for t+1 (hidden under store drain + barrier) ----
    {
      int tn = (t + 1) & (Tx - 1);
      const unsigned short* xrow =
          xT + (size_t)tn * (Bx * INx) + (m0 + col) * INx + quad * 8;
#pragma unroll
      for (int kt = 0; kt < 16; ++kt) xa[kt] = *(const short8*)(xrow + kt * 32);
    }

    __syncthreads();   // drains vmcnt(0) before s_barrier -> h stores visible

    // ---- grid barrier: 8 leaf counters, 16 blocks each, all relaxed ----
    if (tid == 0) {
      __hip_atomic_fetch_add(&bar[(bid & 7) * 32], 1u, __ATOMIC_RELAXED,
                             __HIP_MEMORY_SCOPE_AGENT);
    }
    if (tid < 8) {
      unsigned target = (unsigned)(t + 1) * 16u;
      while (__hip_atomic_load(&bar[tid * 32], __ATOMIC_RELAXED,
                               __HIP_MEMORY_SCOPE_AGENT) < target) {
        __builtin_amdgcn_s_sleep(1);
      }
    }
    __syncthreads();

    // ---- every 32 steps: acquire fence (L2 inv) so no stale line can
    //      survive to an h-buffer address reuse (distance NBUF=65) ----
    if ((t & 31) == 31) {
      __builtin_amdgcn_fence(__ATOMIC_ACQUIRE, "agent");
    }
  }

  // ---- final h -> out [B][1][H] ----
#pragma unroll
  for (int p = 0; p < 2; ++p) {
    int jl = 2 * quad + p;
    out[(m0 + col) * Hx + j0 + jl] = hst[p];
  }
}

extern "C" void kernel_launch(void* const* d_in, const int* in_sizes, int n_in,
                              void* d_out, int out_size, void* d_ws, size_t ws_size,
                              hipStream_t stream) {
  const float* input = (const float*)d_in[0];   // [B][T][IN]
  const float* W_ih  = (const float*)d_in[1];   // [4H][IN]
  const float* W_hh  = (const float*)d_in[2];   // [4H][H]
  const float* b_ih  = (const float*)d_in[3];   // [4H]
  const float* b_hh  = (const float*)d_in[4];   // [4H]
  float* out = (float*)d_out;

  char* ws = (char*)d_ws;
  unsigned int* bar = (unsigned int*)ws;                          // 1 KB
  unsigned short* hbuf = (unsigned short*)(ws + 1024);            // 65 x 128 KB
  unsigned short* xT = (unsigned short*)(ws + (9u << 20));        // 32 MB @ +9 MB

  // zero barrier counters + h buffer 0 (initial state)
  hipMemsetAsync(ws, 0, 1024 + Bx * Hx * sizeof(unsigned short), stream);

  convert_x_kernel<<<(Bx * Tx * INx) / (256 * 8), 256, 0, stream>>>(input, xT);

  lstm_persistent<<<NBLK, 256, 0, stream>>>(W_ih, W_hh, b_ih, b_hh, xT, hbuf, bar, out);
}